// Round 3
// baseline (32.379 us; speedup 1.0000x reference)
//
#include <hip/hip_runtime.h>
#include <math.h>

#define EPSF 1e-8f
#define INV_SQRT2F 0.70710678118654752f
#define INV_SQRT_2PIF 0.39894228040143268f

__device__ inline void max_gauss(float m1, float v1, float m2, float v2,
                                 float& mo, float& vo) {
    float alpha = sqrtf(v1 + v2 + EPSF);
    float beta  = (m1 - m2) / alpha;
    float e     = erff(beta * INV_SQRT2F);
    float cdf_b  = 0.5f * (1.0f + e);
    float cdf_nb = 0.5f * (1.0f - e);
    float pdf_b  = expf(-0.5f * beta * beta) * INV_SQRT_2PIF;
    mo = m1 * cdf_b + m2 * cdf_nb + alpha * pdf_b;
    vo = (v1 + m1 * m1) * cdf_b + (v2 + m2 * m2) * cdf_nb
       + (m1 + m2) * alpha * pdf_b - mo * mo + EPSF;
}

// x: (32, 2, 128, 64, 64) f32; out: (32, 2, 128, 32, 32) f32
// 512 blocks x 512 threads. Block = (b, iq): handles output rows
// i = 2*iq (tile A) and 2*iq+1 (tile B) -> input rows 4iq..4iq+3
// (1 KB contiguous per plane across the two tiles).
// thread: g = t>>5 plane-group [0,16), q = t&31; r = q>>4 row offset,
// qp = q&15 column-quad. Lane's float4: plane p = it*16+g,
// row (4iq + 2*tile + r), cols 4qp..4qp+3.
__global__ __launch_bounds__(512) void dmp_kernel(const float* __restrict__ x,
                                                  float* __restrict__ out) {
    const size_t PL = 4096;  // 64*64 plane

    int blk = blockIdx.x;    // 512
    int b  = blk >> 4;
    int iq = blk & 15;
    int t = threadIdx.x;
    int q = t & 31;
    int g = t >> 5;          // 0..15
    int qp = q & 15;
    int r  = q >> 4;

    const float* baseA = x + ((size_t)b * 256 + (size_t)g) * PL
                           + (size_t)(4 * iq + r) * 64 + (size_t)(4 * qp);
    const float* baseB = baseA + 128;  // +2 rows

    // Issue the entire read burst (32 x float4) before consuming.
    float4 dA[16], dB[16];
    #pragma unroll
    for (int it = 0; it < 16; ++it)
        dA[it] = *(const float4*)(baseA + (size_t)(it * 16) * PL);
    #pragma unroll
    for (int it = 0; it < 16; ++it)
        dB[it] = *(const float4*)(baseB + (size_t)(it * 16) * PL);

    float amA[4] = {0.f,0.f,0.f,0.f}, avA[4] = {0.f,0.f,0.f,0.f};
    float amB[4] = {0.f,0.f,0.f,0.f}, avB[4] = {0.f,0.f,0.f,0.f};
    #pragma unroll
    for (int it = 0; it < 8; ++it) {
        amA[0] += dA[it].x; amA[1] += dA[it].y; amA[2] += dA[it].z; amA[3] += dA[it].w;
        amB[0] += dB[it].x; amB[1] += dB[it].y; amB[2] += dB[it].z; amB[3] += dB[it].w;
    }
    #pragma unroll
    for (int it = 8; it < 16; ++it) {
        avA[0] += dA[it].x; avA[1] += dA[it].y; avA[2] += dA[it].z; avA[3] += dA[it].w;
        avB[0] += dB[it].x; avB[1] += dB[it].y; avB[2] += dB[it].z; avB[3] += dB[it].w;
    }

    __shared__ float red[2][16][32][9];  // pad 9: stride-9 words, gcd(9,32)=1
    #pragma unroll
    for (int k = 0; k < 4; ++k) {
        red[0][g][q][k]     = amA[k];
        red[0][g][q][4 + k] = avA[k];
        red[1][g][q][k]     = amB[k];
        red[1][g][q][4 + k] = avB[k];
    }
    __syncthreads();

    __shared__ float mv[2][2][32];  // [tile][u][j]
    if (t < 64) {
        int tile = t >> 5;
        int j  = t & 31;
        int qh = j >> 1;
        int o  = (j & 1) * 2;
        float sm[2][2] = {{0.f,0.f},{0.f,0.f}};
        float sv[2][2] = {{0.f,0.f},{0.f,0.f}};
        #pragma unroll
        for (int gg = 0; gg < 16; ++gg) {
            #pragma unroll
            for (int rr = 0; rr < 2; ++rr) {
                int qq = rr * 16 + qh;
                sm[rr][0] += red[tile][gg][qq][o];
                sm[rr][1] += red[tile][gg][qq][o + 1];
                sv[rr][0] += red[tile][gg][qq][4 + o];
                sv[rr][1] += red[tile][gg][qq][4 + o + 1];
            }
        }
        float hm1, hv1, hm2, hv2, m, v;
        max_gauss(sm[0][0], sv[0][0], sm[0][1], sv[0][1], hm1, hv1);
        max_gauss(sm[1][0], sv[1][0], sm[1][1], sv[1][1], hm2, hv2);
        max_gauss(hm1, hv1, hm2, hv2, m, v);
        mv[tile][0][j] = m;
        mv[tile][1][j] = v;
    }
    __syncthreads();

    // Store both tiles: 2 x 8192 floats = 4096 float4, 8 iters of 512.
    // Order: jq fastest, then tile (rows i,i+1 contiguous 256 B), then (u,c).
    #pragma unroll
    for (int w = 0; w < 8; ++w) {
        int idx  = w * 512 + t;       // 0..4095
        int jq   = idx & 7;
        int tile = (idx >> 3) & 1;
        int rem  = idx >> 4;          // 0..255
        int u    = rem >> 7;
        int c    = rem & 127;
        float4 val;
        val.x = mv[tile][u][jq * 4 + 0];
        val.y = mv[tile][u][jq * 4 + 1];
        val.z = mv[tile][u][jq * 4 + 2];
        val.w = mv[tile][u][jq * 4 + 3];
        size_t off = (((size_t)b * 2 + u) * 128 + (size_t)c) * 1024
                   + (size_t)(2 * iq + tile) * 32 + (size_t)(jq * 4);
        *(float4*)(out + off) = val;
    }
}

extern "C" void kernel_launch(void* const* d_in, const int* in_sizes, int n_in,
                              void* d_out, int out_size, void* d_ws, size_t ws_size,
                              hipStream_t stream) {
    const float* x = (const float*)d_in[0];
    float* out = (float*)d_out;
    dim3 grid(512), block(512);
    hipLaunchKernelGGL(dmp_kernel, grid, block, 0, stream, x, out);
}

// Round 5
// 31.011 us; speedup vs baseline: 1.0441x; 1.0441x over previous
//
#include <hip/hip_runtime.h>
#include <math.h>

#define EPSF 1e-8f
#define INV_SQRT2F 0.70710678118654752f
#define INV_SQRT_2PIF 0.39894228040143268f

typedef float vf2 __attribute__((ext_vector_type(2)));
typedef float vf4 __attribute__((ext_vector_type(4)));

__device__ inline void max_gauss(float m1, float v1, float m2, float v2,
                                 float& mo, float& vo) {
    float alpha = sqrtf(v1 + v2 + EPSF);
    float beta  = (m1 - m2) / alpha;
    float e     = erff(beta * INV_SQRT2F);
    float cdf_b  = 0.5f * (1.0f + e);
    float cdf_nb = 0.5f * (1.0f - e);
    float pdf_b  = expf(-0.5f * beta * beta) * INV_SQRT_2PIF;
    mo = m1 * cdf_b + m2 * cdf_nb + alpha * pdf_b;
    vo = (v1 + m1 * m1) * cdf_b + (v2 + m2 * m2) * cdf_nb
       + (m1 + m2) * alpha * pdf_b - mo * mo + EPSF;
}

// x: (32, 2, 128, 64, 64) f32; out: (32, 2, 128, 32, 32) f32
// Round-1 winner structure; only change: nontemporal load/store (both
// streams are touch-once -> bypass cache allocation).
// Block = (b, i): 1024 blocks x 256 threads.
// thread = (g = tid>>5 channel-group, j = tid&31 output col)
__global__ __launch_bounds__(256) void dmp_kernel(const float* __restrict__ x,
                                                  float* __restrict__ out) {
    const int C = 128;
    const size_t CH = 4096; // 64*64 plane

    int blk = blockIdx.x;
    int b = blk >> 5;
    int i = blk & 31;
    int t = threadIdx.x;
    int j = t & 31;
    int g = t >> 5;

    // accumulators: m00 m01 m10 m11 v00 v01 v10 v11
    float a[8] = {0.f, 0.f, 0.f, 0.f, 0.f, 0.f, 0.f, 0.f};

    const float* mbase = x + ((size_t)b * 2) * C * CH + (size_t)(g * 16) * CH
                           + (size_t)(2 * i) * 64 + (size_t)(2 * j);
    const float* vbase = mbase + (size_t)C * CH;

    #pragma unroll 4
    for (int c = 0; c < 16; ++c) {
        const float* mp = mbase + (size_t)c * CH;
        const float* vp = vbase + (size_t)c * CH;
        vf2 m0 = __builtin_nontemporal_load((const vf2*)(mp));
        vf2 m1 = __builtin_nontemporal_load((const vf2*)(mp + 64));
        vf2 v0 = __builtin_nontemporal_load((const vf2*)(vp));
        vf2 v1 = __builtin_nontemporal_load((const vf2*)(vp + 64));
        a[0] += m0.x; a[1] += m0.y; a[2] += m1.x; a[3] += m1.y;
        a[4] += v0.x; a[5] += v0.y; a[6] += v1.x; a[7] += v1.y;
    }

    __shared__ float red[8][32][9];  // pad 9 -> conflict-free column reads
    #pragma unroll
    for (int q = 0; q < 8; ++q) red[g][j][q] = a[q];
    __syncthreads();

    __shared__ float mv[2][32];
    if (t < 32) {
        float s[8];
        #pragma unroll
        for (int q = 0; q < 8; ++q) {
            float acc = 0.f;
            #pragma unroll
            for (int gg = 0; gg < 8; ++gg) acc += red[gg][t][q];
            s[q] = acc;
        }
        float hm1, hv1, hm2, hv2, m, v;
        max_gauss(s[0], s[4], s[1], s[5], hm1, hv1);
        max_gauss(s[2], s[6], s[3], s[7], hm2, hv2);
        max_gauss(hm1, hv1, hm2, hv2, m, v);
        mv[0][t] = m;
        mv[1][t] = v;
    }
    __syncthreads();

    // Output: out[((b*2+u)*128 + c)*1024 + i*32 + jj], broadcast over c.
    // 8192 floats = 2048 float4 per block; 8 iterations of 256 threads.
    #pragma unroll
    for (int it = 0; it < 8; ++it) {
        int idx = it * 256 + t;        // 0..2047
        int u   = idx >> 10;           // 0: mean, 1: var
        int rem = idx & 1023;
        int c   = rem >> 3;
        int jq  = rem & 7;             // float4 index within 32-wide row
        vf4 val;
        val.x = mv[u][jq * 4 + 0];
        val.y = mv[u][jq * 4 + 1];
        val.z = mv[u][jq * 4 + 2];
        val.w = mv[u][jq * 4 + 3];
        size_t off = (((size_t)b * 2 + u) * C + c) * 1024 + (size_t)i * 32
                   + (size_t)(jq * 4);
        __builtin_nontemporal_store(val, (vf4*)(out + off));
    }
}

extern "C" void kernel_launch(void* const* d_in, const int* in_sizes, int n_in,
                              void* d_out, int out_size, void* d_ws, size_t ws_size,
                              hipStream_t stream) {
    const float* x = (const float*)d_in[0];
    float* out = (float*)d_out;
    dim3 grid(1024), block(256);
    hipLaunchKernelGGL(dmp_kernel, grid, block, 0, stream, x, out);
}